// Round 5
// baseline (190.209 us; speedup 1.0000x reference)
//
#include <hip/hip_runtime.h>
#include <hip/hip_bf16.h>

#define TPB 256

typedef __attribute__((ext_vector_type(8))) short short8v;   // 8 bf16 (4 VGPRs) MFMA operand
typedef __attribute__((ext_vector_type(4))) float f32x4;     // MFMA accumulator

__device__ __forceinline__ float bf2f(unsigned int u) {
    return __uint_as_float(u << 16);
}
// v_cvt_pk_bf16_f32: lo=bf16(x), hi=bf16(y), RNE rounding, single VALU op.
// (no builtin on gfx950 -- inline asm per T12 recipe)
__device__ __forceinline__ unsigned int packbf(float x, float y) {
    unsigned int r;
    asm("v_cvt_pk_bf16_f32 %0, %1, %2" : "=v"(r) : "v"(x), "v"(y));
    return r;
}
__device__ __forceinline__ short8v pack8(float4 a, float4 bq) {
    union { unsigned int u[4]; short8v s; } c;
    c.u[0] = packbf(a.x, a.y);  c.u[1] = packbf(a.z, a.w);
    c.u[2] = packbf(bq.x, bq.y); c.u[3] = packbf(bq.z, bq.w);
    return c.s;
}

// One block per image, 4 waves. 16 strips of 64 px (2 image rows).
// Wave-private sP/sH rows -> no intra-strip barriers; gating deferred 2 strips
// -> exactly 1 barrier per strip.
__global__ __launch_bounds__(TPB, 2) void nca_mfma(
    const float* __restrict__ state,   // [B,16,32,32]
    const int*   __restrict__ rmask,   // [B,1,32,32]
    const float* __restrict__ w1,      // [128,48]
    const float* __restrict__ b1,      // [128]
    const float* __restrict__ w2,      // [16,128]
    const float* __restrict__ b2,      // [16]
    float* __restrict__ out)           // [B,16,32,32]
{
    __shared__ __align__(16) unsigned short sSt[16 * 34 * 36]; // bf16 state, stride 36, data at [h+1][w+2]
    __shared__ __align__(16) unsigned short sP [64 * 72];      // perception, stride 72 shorts; wave-private rows
    __shared__ __align__(16) unsigned short sH [64 * 136];     // hidden bf16, stride 136; wave-private rows
    __shared__ __align__(16) float          sA [34 * 34];      // new alpha, padded
    __shared__ unsigned char                sPre[1024];        // pre-state alive pool

    const int b    = blockIdx.x;
    const int tid  = threadIdx.x;
    const int lane = tid & 63;
    const int wv   = tid >> 6;     // wave 0..3
    const int lr   = lane & 15;
    const int lg   = lane >> 4;    // 0..3

    // ---------------- weight fragments (registers) ----------------
    // GEMM1 B-frag ntile n: lane holds col j=lr -> feature f=lr*8+n, k=kk*32+lg*8+e (pad 48->64)
    short8v w1f[8][2];
    short8v w2f[4];
    float   b1v[8];
    #pragma unroll
    for (int n = 0; n < 8; ++n) {
        const int f = lr * 8 + n;
        #pragma unroll
        for (int kk = 0; kk < 2; ++kk) {
            const int k0 = kk * 32 + lg * 8;
            if (k0 < 48) {
                const float4 x0 = *reinterpret_cast<const float4*>(w1 + f * 48 + k0);
                const float4 x1 = *reinterpret_cast<const float4*>(w1 + f * 48 + k0 + 4);
                w1f[n][kk] = pack8(x0, x1);
            } else {
                short8v z = {0,0,0,0,0,0,0,0};
                w1f[n][kk] = z;
            }
        }
        b1v[n] = b1[f];
    }
    #pragma unroll
    for (int ks = 0; ks < 4; ++ks) {
        const int k0 = ks * 32 + lg * 8;
        const float4 x0 = *reinterpret_cast<const float4*>(w2 + lr * 128 + k0);
        const float4 x1 = *reinterpret_cast<const float4*>(w2 + lr * 128 + k0 + 4);
        w2f[ks] = pack8(x0, x1);
    }
    const float b2v = b2[lr];

    // ---------------- zero LDS (halos + K-pad + sA borders must be 0) ----------------
    for (int i = tid; i < 16*34*36/2; i += TPB) reinterpret_cast<unsigned int*>(sSt)[i] = 0u;
    for (int i = tid; i < 64*72/2;    i += TPB) reinterpret_cast<unsigned int*>(sP)[i]  = 0u;
    for (int i = tid; i < 34*34;      i += TPB) sA[i] = 0.f;
    __syncthreads();

    // ---------------- stage state -> bf16 LDS (coalesced float4) ----------------
    const float* gs = state + (size_t)b * 16384;
    #pragma unroll
    for (int k = 0; k < 16; ++k) {
        const int q = tid + k * TPB;                 // 0..4095 float4s
        const float4 v = reinterpret_cast<const float4*>(gs)[q];
        const int c = q >> 8, rem = q & 255;
        const int h = rem >> 3, wg = rem & 7;
        const int eo = c * 1224 + (h + 1) * 36 + (wg * 4 + 2);
        reinterpret_cast<unsigned int*>(&sSt[eo])[0] = packbf(v.x, v.y);
        reinterpret_cast<unsigned int*>(&sSt[eo])[1] = packbf(v.z, v.w);
    }
    __syncthreads();

    // ---------------- pre-state alive pool (read before first gate, >=2 barriers later) ----
    for (int p = tid; p < 1024; p += TPB) {
        const int h = p >> 5, w = p & 31;
        const unsigned short* sa = &sSt[3 * 1224 + h * 36 + (w + 1)];
        float m =          bf2f(sa[0]);
        m = fmaxf(m, bf2f(sa[1]));  m = fmaxf(m, bf2f(sa[2]));
        m = fmaxf(m, bf2f(sa[36])); m = fmaxf(m, bf2f(sa[37])); m = fmaxf(m, bf2f(sa[38]));
        m = fmaxf(m, bf2f(sa[72])); m = fmaxf(m, bf2f(sa[73])); m = fmaxf(m, bf2f(sa[74]));
        sPre[p] = (m > 0.1f) ? 1 : 0;
    }

    // gate 64 px of strip with pixel-base pb; this wave's 16 px values in xp[4]
    auto do_gate = [&](int pb, const float* xp) {
        float av = 0.f;
        if (lane < 16) {
            const int p = pb + lane;
            const int h = p >> 5, w = p & 31;
            const float* sa = &sA[h * 34 + w];
            float m =          sa[0];
            m = fmaxf(m, sa[1]);  m = fmaxf(m, sa[2]);
            m = fmaxf(m, sa[34]); m = fmaxf(m, sa[35]); m = fmaxf(m, sa[36]);
            m = fmaxf(m, sa[68]); m = fmaxf(m, sa[69]); m = fmaxf(m, sa[70]);
            av = ((m > 0.1f) && (sPre[p] != 0)) ? 1.f : 0.f;
        }
        const float g0 = __shfl(av, lg * 4 + 0);
        const float g1 = __shfl(av, lg * 4 + 1);
        const float g2 = __shfl(av, lg * 4 + 2);
        const float g3 = __shfl(av, lg * 4 + 3);
        float4 ov;
        ov.x = g0 * fminf(fmaxf(xp[0], 0.f), 1.f);
        ov.y = g1 * fminf(fmaxf(xp[1], 0.f), 1.f);
        ov.z = g2 * fminf(fmaxf(xp[2], 0.f), 1.f);
        ov.w = g3 * fminf(fmaxf(xp[3], 0.f), 1.f);
        *reinterpret_cast<float4*>(&out[(size_t)b * 16384 + lr * 1024 + pb + lg * 4]) = ov;
    };

    float xq[2][4];    // 2-deep strip pipeline of this lane's outputs

    for (int s = 0; s < 16; ++s) {
        const int pbase = s * 64 + wv * 16;
        // prefetch residual-path inputs (consumed ~200 instrs later)
        const int4   mi  = *reinterpret_cast<const int4*>(&rmask[b * 1024 + pbase + lg * 4]);
        const float4 idv = *reinterpret_cast<const float4*>(&state[(size_t)b * 16384 + lr * 1024 + pbase + lg * 4]);

        // ===== [A] perception for THIS WAVE's 16 px (2 px x 2 ch per lane) =====
        {
            const int cg   = lane & 7;        // channel pair
            const int pl   = lane >> 3;       // 0..7 pixel-pair within wave
            const int c0   = cg * 2;
            const int hloc = wv >> 1;         // 0/1
            const int w0   = (wv & 1) * 16 + pl * 2;   // even image col
            const int h    = s * 2 + hloc;    // top row of 3x3 in padded coords
            const int j0   = hloc * 32 + w0;  // strip-local px (even)
            float sx0[2], sx1[2], sy0[2], sy1[2], id0[2], id1[2];
            #pragma unroll
            for (int ci = 0; ci < 2; ++ci) {
                const unsigned short* bp = &sSt[(c0 + ci) * 1224 + h * 36 + w0];
                float A[3], Bv[3], Cv[3], D[3];
                #pragma unroll
                for (int dr = 0; dr < 3; ++dr) {
                    const unsigned int* rp = reinterpret_cast<const unsigned int*>(bp + dr * 36);
                    const unsigned int u0 = rp[0], u1 = rp[1], u2 = rp[2];
                    A[dr]  = bf2f(u0 >> 16);        // image col w0-1
                    Bv[dr] = bf2f(u1 & 0xffffu);    // w0
                    Cv[dr] = bf2f(u1 >> 16);        // w0+1
                    D[dr]  = bf2f(u2 & 0xffffu);    // w0+2
                }
                const float csa = A[0]  + 2.f * A[1]  + A[2];
                const float csb = Bv[0] + 2.f * Bv[1] + Bv[2];
                const float csc = Cv[0] + 2.f * Cv[1] + Cv[2];
                const float csd = D[0]  + 2.f * D[1]  + D[2];
                sx0[ci] = csc - csa;
                sx1[ci] = csd - csb;
                sy0[ci] = (A[2] + 2.f * Bv[2] + Cv[2]) - (A[0] + 2.f * Bv[0] + Cv[0]);
                sy1[ci] = (Bv[2] + 2.f * Cv[2] + D[2]) - (Bv[0] + 2.f * Cv[0] + D[0]);
                id0[ci] = Bv[1];
                id1[ci] = Cv[1];
            }
            unsigned int* r0 = reinterpret_cast<unsigned int*>(&sP[j0 * 72 + c0]);
            unsigned int* r1 = reinterpret_cast<unsigned int*>(&sP[(j0 + 1) * 72 + c0]);
            r0[0]  = packbf(sx0[0], sx0[1]);
            r0[8]  = packbf(sy0[0], sy0[1]);
            r0[16] = packbf(id0[0], id0[1]);
            r1[0]  = packbf(sx1[0], sx1[1]);
            r1[8]  = packbf(sy1[0], sy1[1]);
            r1[16] = packbf(id1[0], id1[1]);
        }
        // no barrier: sP rows j0 are wave-private (lgkmcnt orders within wave)

        // ===== [B] GEMM1 (A rows = this wave's sP rows) =====
        f32x4 acc1[8];
        #pragma unroll
        for (int n = 0; n < 8; ++n) { acc1[n][0]=0.f; acc1[n][1]=0.f; acc1[n][2]=0.f; acc1[n][3]=0.f; }
        #pragma unroll
        for (int kk = 0; kk < 2; ++kk) {
            const short8v a = *reinterpret_cast<const short8v*>(&sP[(wv * 16 + lr) * 72 + kk * 32 + lg * 8]);
            #pragma unroll
            for (int n = 0; n < 8; ++n)
                acc1[n] = __builtin_amdgcn_mfma_f32_16x16x32_bf16(a, w1f[n][kk], acc1[n], 0, 0, 0);
        }
        // epilogue: bias+relu, 8 consecutive features/lane -> one b128 store per r
        #pragma unroll
        for (int r = 0; r < 4; ++r) {
            const int row = wv * 16 + lg * 4 + r;
            uint4 u;
            u.x = packbf(fmaxf(acc1[0][r] + b1v[0], 0.f), fmaxf(acc1[1][r] + b1v[1], 0.f));
            u.y = packbf(fmaxf(acc1[2][r] + b1v[2], 0.f), fmaxf(acc1[3][r] + b1v[3], 0.f));
            u.z = packbf(fmaxf(acc1[4][r] + b1v[4], 0.f), fmaxf(acc1[5][r] + b1v[5], 0.f));
            u.w = packbf(fmaxf(acc1[6][r] + b1v[6], 0.f), fmaxf(acc1[7][r] + b1v[7], 0.f));
            *reinterpret_cast<uint4*>(&sH[row * 136 + lr * 8]) = u;
        }
        // no barrier: sH rows are wave-private

        // ===== [C] GEMM2 + exact-f32 residual =====
        f32x4 acc2; acc2[0]=0.f; acc2[1]=0.f; acc2[2]=0.f; acc2[3]=0.f;
        #pragma unroll
        for (int ksx = 0; ksx < 4; ++ksx) {
            const short8v a2 = *reinterpret_cast<const short8v*>(&sH[(wv * 16 + lr) * 136 + ksx * 32 + lg * 8]);
            acc2 = __builtin_amdgcn_mfma_f32_16x16x32_bf16(a2, w2f[ksx], acc2, 0, 0, 0);
        }
        float xv[4];
        xv[0] = fmaf(acc2[0] + b2v, (float)mi.x, idv.x);
        xv[1] = fmaf(acc2[1] + b2v, (float)mi.y, idv.y);
        xv[2] = fmaf(acc2[2] + b2v, (float)mi.z, idv.z);
        xv[3] = fmaf(acc2[3] + b2v, (float)mi.w, idv.w);
        if (lr == 3) {                       // new alpha -> sA (rows 2s, 2s+1)
            const int p0 = pbase + lg * 4;
            const int h2 = p0 >> 5, w2c = p0 & 31;
            float* dst = &sA[(h2 + 1) * 34 + (w2c + 1)];
            dst[0] = xv[0]; dst[1] = xv[1]; dst[2] = xv[2]; dst[3] = xv[3];
        }

        // ===== [D] gate strip s-2 (alpha rows <= 2s-2 complete since last barrier) =====
        const int par = s & 1;
        if (s >= 2) do_gate((s - 2) * 64 + wv * 16, xq[par]);
        xq[par][0] = xv[0]; xq[par][1] = xv[1]; xq[par][2] = xv[2]; xq[par][3] = xv[3];

        __syncthreads();   // the ONE barrier per strip: publishes this strip's sA
    }
    // drain the 2-strip pipeline (strip 15's barrier already executed)
    do_gate(14 * 64 + wv * 16, xq[0]);
    do_gate(15 * 64 + wv * 16, xq[1]);
}

extern "C" void kernel_launch(void* const* d_in, const int* in_sizes, int n_in,
                              void* d_out, int out_size, void* d_ws, size_t ws_size,
                              hipStream_t stream) {
    const float* state = (const float*)d_in[0];
    const int*   rmask = (const int*)d_in[1];
    const float* w1    = (const float*)d_in[2];
    const float* b1    = (const float*)d_in[3];
    const float* w2    = (const float*)d_in[4];
    const float* b2    = (const float*)d_in[5];
    float* outp = (float*)d_out;

    const int B = in_sizes[0] / (16 * 32 * 32);   // 1024
    hipLaunchKernelGGL(nca_mfma, dim3(B), dim3(TPB), 0, stream,
                       state, rmask, w1, b1, w2, b2, outp);
}